// Round 1
// baseline (279.618 us; speedup 1.0000x reference)
//
#include <hip/hip_runtime.h>
#include <hip/hip_bf16.h>

// Problem constants
#define B_      4
#define T_      1024
#define NTOK    4096      // B*T
#define D_      512
#define E_      10
#define H_      2048
#define LIN_    928
#define TOPK    2
#define BM      64        // GEMM row tile
#define ROWS_CAP 8832     // NTOK*TOPK + E_*BM  (per-expert padding to BM)
#define TILES_CAP 144     // >= sum ceil(n_e/BM) <= 128 + 10

typedef __bf16 bf16x8 __attribute__((ext_vector_type(8)));
typedef float  f32x4  __attribute__((ext_vector_type(4)));

// ---- workspace layout (bytes) ----
#define OFF_W1T   0ull
#define SZ_W1T    (10ull*2048*512*2)            // 20,971,520
#define OFF_W2T   (OFF_W1T + SZ_W1T)
#define SZ_W2T    SZ_W1T
#define OFF_XG    (OFF_W2T + SZ_W2T)            // 41,943,040
#define SZ_XG     ((size_t)ROWS_CAP*512*2)      // 9,043,968
#define OFF_HID   (OFF_XG + SZ_XG)              // 50,987,008
#define SZ_HID    ((size_t)ROWS_CAP*2048*2)     // 36,175,872
#define OFF_Y     (OFF_HID + SZ_HID)            // 87,162,880
#define SZ_Y      ((size_t)ROWS_CAP*512*4)      // 18,087,936
#define OFF_TOKE  (OFF_Y + SZ_Y)
#define OFF_TOKG  (OFF_TOKE + 32768)
#define OFF_TROWS (OFF_TOKG + 32768)
#define OFF_RTOK  (OFF_TROWS + 32768)
#define OFF_CNT   (OFF_RTOK + 35328)
#define OFF_CUR   (OFF_CNT + 64)
#define OFF_OFFS  (OFF_CUR + 64)
#define OFF_TE    (OFF_OFFS + 64)
#define OFF_TR    (OFF_TE + 640)
// total ~105.4 MB

static __device__ __forceinline__ unsigned short f2b(float f) {
  // fp32 -> bf16 round-to-nearest-even (finite values)
  unsigned int u = __float_as_uint(f);
  unsigned int r = (u + 0x7fffu + ((u >> 16) & 1u)) >> 16;
  return (unsigned short)r;
}

// ---------------- init: counts=0, row_token=-1 ----------------
__global__ void init_k(int* __restrict__ row_token, int* __restrict__ counts) {
  int i = blockIdx.x * 256 + threadIdx.x;
  if (i < ROWS_CAP) row_token[i] = -1;
  if (i < E_) counts[i] = 0;
}

// ---------------- router: fp32, 1 wave per token ----------------
__global__ void router_k(const float* __restrict__ x, const float* __restrict__ dt,
                         const float* __restrict__ dd, const float* __restrict__ dr,
                         const float* __restrict__ de, const float* __restrict__ cemb,
                         const int* __restrict__ city,
                         const float* __restrict__ Wg, const float* __restrict__ bg,
                         const float* __restrict__ Wn, const float* __restrict__ bn,
                         const float* __restrict__ noise,
                         float* __restrict__ gate1, int* __restrict__ tok_e,
                         float* __restrict__ tok_g, int* __restrict__ counts) {
  int n = blockIdx.x;           // token
  int lane = threadIdx.x;       // 0..63
  int b = n >> 10;              // T_=1024
  int cb = city[b];
  float lp[E_], npp[E_];
#pragma unroll
  for (int e = 0; e < E_; e++) { lp[e] = 0.f; npp[e] = 0.f; }
  for (int c = lane; c < LIN_; c += 64) {
    float v;
    if (c < 512)      v = x[(size_t)n * 512 + c];
    else if (c < 544) v = cemb[cb * 32 + (c - 512)];
    else if (c < 672) v = dt[(size_t)n * 128 + (c - 544)];
    else if (c < 800) v = dd[(size_t)n * 128 + (c - 672)];
    else if (c < 864) v = dr[(size_t)n * 64 + (c - 800)];
    else              v = de[(size_t)n * 64 + (c - 864)];
#pragma unroll
    for (int e = 0; e < E_; e++) {
      lp[e]  = fmaf(v, Wg[e * LIN_ + c], lp[e]);
      npp[e] = fmaf(v, Wn[e * LIN_ + c], npp[e]);
    }
  }
#pragma unroll
  for (int off = 32; off; off >>= 1) {
#pragma unroll
    for (int e = 0; e < E_; e++) {
      lp[e]  += __shfl_xor(lp[e], off);
      npp[e] += __shfl_xor(npp[e], off);
    }
  }
  if (lane == 0) {
    float logits[E_], noisy[E_], ex[E_];
    float mx = -3.4e38f;
#pragma unroll
    for (int e = 0; e < E_; e++) { logits[e] = lp[e] + bg[e]; mx = fmaxf(mx, logits[e]); }
    float s = 0.f;
#pragma unroll
    for (int e = 0; e < E_; e++) { ex[e] = expf(logits[e] - mx); s += ex[e]; }
    float invs = 1.f / s;
#pragma unroll
    for (int e = 0; e < E_; e++) gate1[(size_t)n * E_ + e] = ex[e] * invs;
#pragma unroll
    for (int e = 0; e < E_; e++) {
      float t = npp[e] + bn[e];
      float sp = (t > 20.f) ? t : log1pf(expf(t));   // softplus
      noisy[e] = logits[e] + noise[(size_t)n * E_ + e] * sp;
    }
    // top-2, ties -> lowest index (matches lax.top_k)
    int i0 = 0; float v0 = noisy[0];
    for (int e = 1; e < E_; e++) if (noisy[e] > v0) { v0 = noisy[e]; i0 = e; }
    int i1 = -1; float v1 = -3.4e38f;
    for (int e = 0; e < E_; e++) if (e != i0 && noisy[e] > v1) { v1 = noisy[e]; i1 = e; }
    float ee = expf(v1 - v0);
    float g0 = 1.f / (1.f + ee);
    tok_e[2 * n] = i0; tok_e[2 * n + 1] = i1;
    tok_g[2 * n] = g0; tok_g[2 * n + 1] = ee * g0;
    atomicAdd(&counts[i0], 1); atomicAdd(&counts[i1], 1);
  }
}

// ---------------- setup: prefix sum (padded to BM), tile tables ----------------
__global__ void setup_k(const int* __restrict__ counts, int* __restrict__ offsets,
                        int* __restrict__ cursors, int* __restrict__ tile_e,
                        int* __restrict__ tile_r0) {
  if (threadIdx.x == 0) {
    int off = 0, tt = 0;
    for (int e = 0; e < E_; e++) {
      offsets[e] = off; cursors[e] = off;
      int ne = counts[e];
      int nt = (ne + BM - 1) / BM;
      for (int i = 0; i < nt; i++) { tile_e[tt] = e; tile_r0[tt] = off + i * BM; tt++; }
      off += nt * BM;
    }
    offsets[E_] = off;
    for (; tt < TILES_CAP; tt++) { tile_e[tt] = -1; tile_r0[tt] = 0; }
  }
}

// ---------------- scatter: token -> grouped row ----------------
__global__ void scatter_k(const int* __restrict__ tok_e, int* __restrict__ cursors,
                          int* __restrict__ row_token, int* __restrict__ token_rows) {
  int n = blockIdx.x * blockDim.x + threadIdx.x;
  if (n >= NTOK) return;
  for (int k = 0; k < TOPK; k++) {
    int e = tok_e[2 * n + k];
    int pos = atomicAdd(&cursors[e], 1);
    row_token[pos] = n;
    token_rows[2 * n + k] = pos;
  }
}

// ---------------- gather x rows -> bf16 (padding rows -> 0) ----------------
__global__ void gather_k(const float* __restrict__ x, const int* __restrict__ row_token,
                         unsigned short* __restrict__ xg) {
  int r = blockIdx.x;
  int c = threadIdx.x * 4;   // 128 threads
  int t = row_token[r];
  float4 v = make_float4(0.f, 0.f, 0.f, 0.f);
  if (t >= 0) v = *(const float4*)&x[(size_t)t * D_ + c];
  ushort4 o;
  o.x = f2b(v.x); o.y = f2b(v.y); o.z = f2b(v.z); o.w = f2b(v.w);
  *(ushort4*)&xg[(size_t)r * D_ + c] = o;
}

// ---------------- weight convert + transpose: [E][R][C] f32 -> [E][C][R] bf16 ----------------
__global__ void wconv_k(const float* __restrict__ src, unsigned short* __restrict__ dst,
                        int R, int C) {
  __shared__ float t[32][33];
  int e = blockIdx.z;
  int c0 = blockIdx.x << 5, r0 = blockIdx.y << 5;
  int tx = threadIdx.x & 31, tg = threadIdx.x >> 5;   // tg 0..7
  const float* s = src + ((size_t)e * R + r0) * C + c0;
#pragma unroll
  for (int i = 0; i < 4; i++) { int r = tg + i * 8; t[r][tx] = s[(size_t)r * C + tx]; }
  __syncthreads();
  unsigned short* d = dst + ((size_t)e * C + c0) * R + r0;
#pragma unroll
  for (int i = 0; i < 4; i++) { int r = tg + i * 8; d[(size_t)r * R + tx] = f2b(t[tx][r]); }
}

// ---------------- grouped GEMM: C[64x128] = A[64xKD] * BT[ND rows][KD]^T ----------------
// MODE 0: out_bf16 = gelu(acc + bias[e][col])   (GEMM1 -> hid)
// MODE 1: out_f32  = acc                        (GEMM2 -> y)
template<int KD, int ND, int MODE>
__global__ __launch_bounds__(256) void gemm_k(
    const unsigned short* __restrict__ A, const unsigned short* __restrict__ BT,
    const float* __restrict__ bias, unsigned short* __restrict__ outb,
    float* __restrict__ outf,
    const int* __restrict__ tile_e, const int* __restrict__ tile_r0) {
  int e = tile_e[blockIdx.y];
  if (e < 0) return;
  int row0 = tile_r0[blockIdx.y];
  int n0 = blockIdx.x * 128;
  int tid = threadIdx.x;
  int lane = tid & 63, wid = tid >> 6;
  int wr = wid >> 1, wc = wid & 1;         // 2x2 waves, each 32x64
  __shared__ __align__(16) unsigned short As[64][40];   // +16B pad per row
  __shared__ __align__(16) unsigned short Bs[128][40];
  f32x4 acc[2][4] = {};
  const unsigned short* Ab = A + (size_t)row0 * KD;
  const unsigned short* Bb = BT + ((size_t)e * ND + n0) * KD;
  int ar = tid >> 2, asg = (tid & 3) * 8;
  int g = (lane >> 4) * 8, r = lane & 15;
  for (int k0 = 0; k0 < KD; k0 += 32) {
    if (k0) __syncthreads();
    *(bf16x8*)&As[ar][asg] = *(const bf16x8*)&Ab[(size_t)ar * KD + k0 + asg];
#pragma unroll
    for (int i = 0; i < 2; i++) {
      int cid = tid + i * 256;
      *(bf16x8*)&Bs[cid >> 2][(cid & 3) * 8] =
          *(const bf16x8*)&Bb[(size_t)(cid >> 2) * KD + k0 + (cid & 3) * 8];
    }
    __syncthreads();
    bf16x8 av[2], bv[4];
#pragma unroll
    for (int mi = 0; mi < 2; mi++) av[mi] = *(const bf16x8*)&As[wr * 32 + mi * 16 + r][g];
#pragma unroll
    for (int ni = 0; ni < 4; ni++) bv[ni] = *(const bf16x8*)&Bs[wc * 64 + ni * 16 + r][g];
#pragma unroll
    for (int mi = 0; mi < 2; mi++)
#pragma unroll
      for (int ni = 0; ni < 4; ni++)
        acc[mi][ni] = __builtin_amdgcn_mfma_f32_16x16x32_bf16(av[mi], bv[ni], acc[mi][ni], 0, 0, 0);
  }
  // C/D layout (m89-verified): col = lane&15, row = (lane>>4)*4 + reg
  int rq = (lane >> 4) * 4;
#pragma unroll
  for (int mi = 0; mi < 2; mi++) {
#pragma unroll
    for (int ni = 0; ni < 4; ni++) {
      int col = n0 + wc * 64 + ni * 16 + r;
#pragma unroll
      for (int q = 0; q < 4; q++) {
        int row = row0 + wr * 32 + mi * 16 + rq + q;
        float v = acc[mi][ni][q];
        if constexpr (MODE == 0) {
          v += bias[e * ND + col];
          v = 0.5f * v * (1.f + erff(v * 0.70710678118654752440f));   // exact gelu
          outb[(size_t)row * ND + col] = f2b(v);
        } else {
          outf[(size_t)row * ND + col] = v;
        }
      }
    }
  }
}

// ---------------- combine: out[n] = g0*(y[r0]+b2[e0]) + g1*(y[r1]+b2[e1]) ----------------
__global__ void combine_k(const float* __restrict__ y, const float* __restrict__ b2,
                          const int* __restrict__ token_rows, const int* __restrict__ tok_e,
                          const float* __restrict__ tok_g, float* __restrict__ out) {
  int gid = blockIdx.x * 256 + threadIdx.x;   // NTOK*D_/4 = 524288 total
  int n = gid >> 7;
  int c = (gid & 127) << 2;
  int r0 = token_rows[2 * n], r1 = token_rows[2 * n + 1];
  int e0 = tok_e[2 * n], e1 = tok_e[2 * n + 1];
  float g0 = tok_g[2 * n], g1 = tok_g[2 * n + 1];
  float4 y0 = *(const float4*)&y[(size_t)r0 * D_ + c];
  float4 y1 = *(const float4*)&y[(size_t)r1 * D_ + c];
  float4 c0 = *(const float4*)&b2[e0 * D_ + c];
  float4 c1 = *(const float4*)&b2[e1 * D_ + c];
  float4 o;
  o.x = g0 * (y0.x + c0.x) + g1 * (y1.x + c1.x);
  o.y = g0 * (y0.y + c0.y) + g1 * (y1.y + c1.y);
  o.z = g0 * (y0.z + c0.z) + g1 * (y1.z + c1.z);
  o.w = g0 * (y0.w + c0.w) + g1 * (y1.w + c1.w);
  *(float4*)&out[(size_t)n * D_ + c] = o;
}

extern "C" void kernel_launch(void* const* d_in, const int* in_sizes, int n_in,
                              void* d_out, int out_size, void* d_ws, size_t ws_size,
                              hipStream_t stream) {
  const float* x     = (const float*)d_in[0];
  const float* dt    = (const float*)d_in[1];
  const float* dd    = (const float*)d_in[2];
  const float* dr    = (const float*)d_in[3];
  const float* de    = (const float*)d_in[4];
  const float* cemb  = (const float*)d_in[5];
  const float* Wg    = (const float*)d_in[6];
  const float* bg    = (const float*)d_in[7];
  const float* Wn    = (const float*)d_in[8];
  const float* bn    = (const float*)d_in[9];
  const float* W1    = (const float*)d_in[10];
  const float* b1    = (const float*)d_in[11];
  const float* W2    = (const float*)d_in[12];
  const float* b2    = (const float*)d_in[13];
  const float* noise = (const float*)d_in[14];
  const int*   city  = (const int*)d_in[15];

  float* out   = (float*)d_out;
  float* gate1 = out + (size_t)NTOK * D_;

  char* ws = (char*)d_ws;
  unsigned short* w1T = (unsigned short*)(ws + OFF_W1T);   // [E][H][D] bf16
  unsigned short* w2T = (unsigned short*)(ws + OFF_W2T);   // [E][D][H] bf16
  unsigned short* xg  = (unsigned short*)(ws + OFF_XG);    // [ROWS_CAP][D] bf16
  unsigned short* hid = (unsigned short*)(ws + OFF_HID);   // [ROWS_CAP][H] bf16
  float*  yb          = (float*)(ws + OFF_Y);              // [ROWS_CAP][D] f32
  int*    tok_e       = (int*)(ws + OFF_TOKE);
  float*  tok_g       = (float*)(ws + OFF_TOKG);
  int*    token_rows  = (int*)(ws + OFF_TROWS);
  int*    row_token   = (int*)(ws + OFF_RTOK);
  int*    counts      = (int*)(ws + OFF_CNT);
  int*    cursors     = (int*)(ws + OFF_CUR);
  int*    offsets     = (int*)(ws + OFF_OFFS);
  int*    tile_e      = (int*)(ws + OFF_TE);
  int*    tile_r0     = (int*)(ws + OFF_TR);

  init_k<<<(ROWS_CAP + 255) / 256, 256, 0, stream>>>(row_token, counts);
  router_k<<<NTOK, 64, 0, stream>>>(x, dt, dd, dr, de, cemb, city, Wg, bg, Wn, bn,
                                    noise, gate1, tok_e, tok_g, counts);
  setup_k<<<1, 64, 0, stream>>>(counts, offsets, cursors, tile_e, tile_r0);
  scatter_k<<<16, 256, 0, stream>>>(tok_e, cursors, row_token, token_rows);
  gather_k<<<ROWS_CAP, 128, 0, stream>>>(x, row_token, xg);
  wconv_k<<<dim3(64, 16, E_), 256, 0, stream>>>(W1, w1T, 512, 2048);   // W1 [E][512][2048] -> [E][2048][512]
  wconv_k<<<dim3(16, 64, E_), 256, 0, stream>>>(W2, w2T, 2048, 512);   // W2 [E][2048][512] -> [E][512][2048]
  gemm_k<512, 2048, 0><<<dim3(16, TILES_CAP), 256, 0, stream>>>(xg, w1T, b1, hid, nullptr, tile_e, tile_r0);
  gemm_k<2048, 512, 1><<<dim3(4, TILES_CAP), 256, 0, stream>>>(hid, w2T, nullptr, nullptr, yb, tile_e, tile_r0);
  combine_k<<<2048, 256, 0, stream>>>(yb, b2, token_rows, tok_e, tok_g, out);
}

// Round 2
// 211.288 us; speedup vs baseline: 1.3234x; 1.3234x over previous
//
#include <hip/hip_runtime.h>
#include <hip/hip_bf16.h>

// Problem constants
#define B_      4
#define T_      1024
#define NTOK    4096      // B*T
#define D_      512
#define E_      10
#define H_      2048
#define LIN_    928
#define TOPK    2
#define BM      64        // GEMM row tile
#define ROWS_CAP 8832     // NTOK*TOPK + E_*BM  (per-expert padding to BM)
#define TILES_CAP 144     // >= sum ceil(n_e/BM) <= 128 + 10

typedef __bf16 bf16x8 __attribute__((ext_vector_type(8)));
typedef float  f32x4  __attribute__((ext_vector_type(4)));

// ---- workspace layout (bytes) ----
#define OFF_W1T   0ull
#define SZ_W1T    (10ull*2048*512*2)            // 20,971,520
#define OFF_W2T   (OFF_W1T + SZ_W1T)
#define SZ_W2T    SZ_W1T
#define OFF_XG    (OFF_W2T + SZ_W2T)            // 41,943,040
#define SZ_XG     ((size_t)ROWS_CAP*512*2)      // 9,043,968
#define OFF_HID   (OFF_XG + SZ_XG)              // 50,987,008
#define SZ_HID    ((size_t)ROWS_CAP*2048*2)     // 36,175,872
#define OFF_Y     (OFF_HID + SZ_HID)            // 87,162,880
#define SZ_Y      ((size_t)ROWS_CAP*512*4)      // 18,087,936
#define OFF_TOKE  (OFF_Y + SZ_Y)
#define OFF_TOKG  (OFF_TOKE + 32768)
#define OFF_TROWS (OFF_TOKG + 32768)
#define OFF_RTOK  (OFF_TROWS + 32768)
#define OFF_CNT   (OFF_RTOK + 35328)
#define OFF_CUR   (OFF_CNT + 64)
#define OFF_OFFS  (OFF_CUR + 64)
#define OFF_TE    (OFF_OFFS + 64)
#define OFF_TR    (OFF_TE + 640)
// total ~105.4 MB
// logits scratch (4096*20 f32 = 328 KB) aliased onto the hid region:
// hid is only written by gemm1 (after route2 consumed logits).

static __device__ __forceinline__ unsigned short f2b(float f) {
  // fp32 -> bf16 round-to-nearest-even (finite values)
  unsigned int u = __float_as_uint(f);
  unsigned int r = (u + 0x7fffu + ((u >> 16) & 1u)) >> 16;
  return (unsigned short)r;
}

// ---------------- router main: raw gate/noise sums, fp32 ----------------
// grid 256 x 256thr; each wave computes 4 tokens x 20 outputs.
// Also folds in the old init_k (row_token=-1, counts=0).
__global__ __launch_bounds__(256) void router_k(
    const float* __restrict__ x, const float* __restrict__ dt,
    const float* __restrict__ dd, const float* __restrict__ dr,
    const float* __restrict__ de, const float* __restrict__ cemb,
    const int* __restrict__ city,
    const float* __restrict__ Wg, const float* __restrict__ Wn,
    float* __restrict__ logits_all, int* __restrict__ row_token,
    int* __restrict__ counts) {
  int tid = threadIdx.x;
  int gi = blockIdx.x * 256 + tid;
  if (gi < ROWS_CAP) row_token[gi] = -1;
  if (gi < E_) counts[gi] = 0;

  int lane = tid & 63;
  int gw = blockIdx.x * 4 + (tid >> 6);   // global wave 0..1023
  int n0 = gw * 4;                        // 4 tokens per wave
  int b = n0 >> 10;
  int cb = city[b];

  float acc[4][20];
#pragma unroll
  for (int j = 0; j < 4; j++)
#pragma unroll
    for (int o = 0; o < 20; o++) acc[j][o] = 0.f;

  // city segment (cols 512..543), same value for all 4 tokens
  {
    float hce = (lane < 32) ? cemb[cb * 32 + lane] : 0.f;
    int c = 512 + (lane & 31);
#pragma unroll
    for (int o = 0; o < 10; o++) {
      float wg = Wg[o * LIN_ + c];
      float wn = Wn[o * LIN_ + c];
#pragma unroll
      for (int j = 0; j < 4; j++) {
        acc[j][o]      = fmaf(hce, wg, acc[j][o]);
        acc[j][10 + o] = fmaf(hce, wn, acc[j][10 + o]);
      }
    }
  }

  // 5 contiguous segments: {ptr, width, col offset}
#pragma unroll
  for (int s = 0; s < 5; s++) {
    const float* hp; int W, cofs;
    if      (s == 0) { hp = x;  W = 512; cofs = 0;   }
    else if (s == 1) { hp = dt; W = 128; cofs = 544; }
    else if (s == 2) { hp = dd; W = 128; cofs = 672; }
    else if (s == 3) { hp = dr; W = 64;  cofs = 800; }
    else             { hp = de; W = 64;  cofs = 864; }
    for (int base = 0; base < W; base += 64) {
      int c = cofs + base + lane;
      float wv[20];
#pragma unroll
      for (int o = 0; o < 10; o++) {
        wv[o]      = Wg[o * LIN_ + c];
        wv[10 + o] = Wn[o * LIN_ + c];
      }
      float hv[4];
#pragma unroll
      for (int j = 0; j < 4; j++) hv[j] = hp[(size_t)(n0 + j) * W + base + lane];
#pragma unroll
      for (int j = 0; j < 4; j++)
#pragma unroll
        for (int o = 0; o < 20; o++) acc[j][o] = fmaf(hv[j], wv[o], acc[j][o]);
    }
  }

  // cross-lane butterfly reduce (all lanes end with full sums)
#pragma unroll
  for (int off = 1; off < 64; off <<= 1) {
#pragma unroll
    for (int j = 0; j < 4; j++)
#pragma unroll
      for (int o = 0; o < 20; o++) acc[j][o] += __shfl_xor(acc[j][o], off);
  }

  // lanes 0..19 store token j's 20 sums (predicated select, coalesced store)
#pragma unroll
  for (int j = 0; j < 4; j++) {
    float v = 0.f;
#pragma unroll
    for (int o = 0; o < 20; o++) if (lane == o) v = acc[j][o];
    if (lane < 20) logits_all[(size_t)(n0 + j) * 20 + lane] = v;
  }
}

// ---------------- router epilogue: softmax/gate1, noisy top-2 ----------------
__global__ void route2_k(const float* __restrict__ logits_all,
                         const float* __restrict__ bg, const float* __restrict__ bn,
                         const float* __restrict__ noise,
                         float* __restrict__ gate1, int* __restrict__ tok_e,
                         float* __restrict__ tok_g, int* __restrict__ counts) {
  int n = blockIdx.x * 256 + threadIdx.x;
  if (n >= NTOK) return;
  const float* p = &logits_all[(size_t)n * 20];
  float logits[E_], noisy[E_], ex[E_];
  float mx = -3.4e38f;
#pragma unroll
  for (int e = 0; e < E_; e++) { logits[e] = p[e] + bg[e]; mx = fmaxf(mx, logits[e]); }
  float s = 0.f;
#pragma unroll
  for (int e = 0; e < E_; e++) { ex[e] = expf(logits[e] - mx); s += ex[e]; }
  float invs = 1.f / s;
#pragma unroll
  for (int e = 0; e < E_; e++) gate1[(size_t)n * E_ + e] = ex[e] * invs;
#pragma unroll
  for (int e = 0; e < E_; e++) {
    float t = p[10 + e] + bn[e];
    float sp = (t > 20.f) ? t : log1pf(expf(t));   // softplus
    noisy[e] = logits[e] + noise[(size_t)n * E_ + e] * sp;
  }
  // top-2, ties -> lowest index (matches lax.top_k)
  int i0 = 0; float v0 = noisy[0];
#pragma unroll
  for (int e = 1; e < E_; e++) if (noisy[e] > v0) { v0 = noisy[e]; i0 = e; }
  int i1 = -1; float v1 = -3.4e38f;
#pragma unroll
  for (int e = 0; e < E_; e++) if (e != i0 && noisy[e] > v1) { v1 = noisy[e]; i1 = e; }
  float ee = expf(v1 - v0);
  float g0 = 1.f / (1.f + ee);
  tok_e[2 * n] = i0; tok_e[2 * n + 1] = i1;
  tok_g[2 * n] = g0; tok_g[2 * n + 1] = ee * g0;
  atomicAdd(&counts[i0], 1); atomicAdd(&counts[i1], 1);
}

// ---------------- setup: prefix sum (padded to BM), tile tables ----------------
__global__ void setup_k(const int* __restrict__ counts, int* __restrict__ offsets,
                        int* __restrict__ cursors, int* __restrict__ tile_e,
                        int* __restrict__ tile_r0) {
  __shared__ int cnt[E_], pf[E_ + 1], tb[E_ + 1];
  int tid = threadIdx.x;
  if (tid < E_) cnt[tid] = counts[tid];
  __syncthreads();
  if (tid == 0) {
    int off = 0, tt = 0;
    for (int e = 0; e < E_; e++) {
      pf[e] = off; tb[e] = tt;
      int nt = (cnt[e] + BM - 1) / BM;
      tt += nt; off += nt * BM;
    }
    pf[E_] = off; tb[E_] = tt;
  }
  __syncthreads();
  if (tid < E_) { offsets[tid] = pf[tid]; cursors[tid] = pf[tid]; }
  if (tid == E_) offsets[E_] = pf[E_];
  if (tid < TILES_CAP) {
    int e = -1;
#pragma unroll
    for (int k = 0; k < E_; k++) if (tid >= tb[k] && tid < tb[k + 1]) e = k;
    if (e >= 0) { tile_e[tid] = e; tile_r0[tid] = pf[e] + (tid - tb[e]) * BM; }
    else        { tile_e[tid] = -1; tile_r0[tid] = 0; }
  }
}

// ---------------- scatter: token -> grouped row ----------------
__global__ void scatter_k(const int* __restrict__ tok_e, int* __restrict__ cursors,
                          int* __restrict__ row_token, int* __restrict__ token_rows) {
  int n = blockIdx.x * blockDim.x + threadIdx.x;
  if (n >= NTOK) return;
  for (int k = 0; k < TOPK; k++) {
    int e = tok_e[2 * n + k];
    int pos = atomicAdd(&cursors[e], 1);
    row_token[pos] = n;
    token_rows[2 * n + k] = pos;
  }
}

// ---------------- gather x rows -> bf16 (padding rows -> 0) ----------------
__global__ void gather_k(const float* __restrict__ x, const int* __restrict__ row_token,
                         unsigned short* __restrict__ xg) {
  int r = blockIdx.x;
  int c = threadIdx.x * 4;   // 128 threads
  int t = row_token[r];
  float4 v = make_float4(0.f, 0.f, 0.f, 0.f);
  if (t >= 0) v = *(const float4*)&x[(size_t)t * D_ + c];
  ushort4 o;
  o.x = f2b(v.x); o.y = f2b(v.y); o.z = f2b(v.z); o.w = f2b(v.w);
  *(ushort4*)&xg[(size_t)r * D_ + c] = o;
}

// ---------------- weight convert + transpose: [E][R][C] f32 -> [E][C][R] bf16 ----------------
__global__ void wconv_k(const float* __restrict__ src, unsigned short* __restrict__ dst,
                        int R, int C) {
  __shared__ float t[32][33];
  int e = blockIdx.z;
  int c0 = blockIdx.x << 5, r0 = blockIdx.y << 5;
  int tx = threadIdx.x & 31, tg = threadIdx.x >> 5;   // tg 0..7
  const float* s = src + ((size_t)e * R + r0) * C + c0;
#pragma unroll
  for (int i = 0; i < 4; i++) { int r = tg + i * 8; t[r][tx] = s[(size_t)r * C + tx]; }
  __syncthreads();
  unsigned short* d = dst + ((size_t)e * C + c0) * R + r0;
#pragma unroll
  for (int i = 0; i < 4; i++) { int r = tg + i * 8; d[(size_t)r * R + tx] = f2b(t[tx][r]); }
}

// ---------------- grouped GEMM: C[64x128] = A[64xKD] * BT[ND rows][KD]^T ----------------
// MODE 0: out_bf16 = gelu(acc + bias[e][col])   (GEMM1 -> hid)
// MODE 1: out_f32  = acc                        (GEMM2 -> y)
template<int KD, int ND, int MODE>
__global__ __launch_bounds__(256) void gemm_k(
    const unsigned short* __restrict__ A, const unsigned short* __restrict__ BT,
    const float* __restrict__ bias, unsigned short* __restrict__ outb,
    float* __restrict__ outf,
    const int* __restrict__ tile_e, const int* __restrict__ tile_r0) {
  int e = tile_e[blockIdx.y];
  if (e < 0) return;
  int row0 = tile_r0[blockIdx.y];
  int n0 = blockIdx.x * 128;
  int tid = threadIdx.x;
  int lane = tid & 63, wid = tid >> 6;
  int wr = wid >> 1, wc = wid & 1;         // 2x2 waves, each 32x64
  __shared__ __align__(16) unsigned short As[64][40];   // +16B pad per row
  __shared__ __align__(16) unsigned short Bs[128][40];
  f32x4 acc[2][4] = {};
  const unsigned short* Ab = A + (size_t)row0 * KD;
  const unsigned short* Bb = BT + ((size_t)e * ND + n0) * KD;
  int ar = tid >> 2, asg = (tid & 3) * 8;
  int g = (lane >> 4) * 8, r = lane & 15;
  for (int k0 = 0; k0 < KD; k0 += 32) {
    if (k0) __syncthreads();
    *(bf16x8*)&As[ar][asg] = *(const bf16x8*)&Ab[(size_t)ar * KD + k0 + asg];
#pragma unroll
    for (int i = 0; i < 2; i++) {
      int cid = tid + i * 256;
      *(bf16x8*)&Bs[cid >> 2][(cid & 3) * 8] =
          *(const bf16x8*)&Bb[(size_t)(cid >> 2) * KD + k0 + (cid & 3) * 8];
    }
    __syncthreads();
    bf16x8 av[2], bv[4];
#pragma unroll
    for (int mi = 0; mi < 2; mi++) av[mi] = *(const bf16x8*)&As[wr * 32 + mi * 16 + r][g];
#pragma unroll
    for (int ni = 0; ni < 4; ni++) bv[ni] = *(const bf16x8*)&Bs[wc * 64 + ni * 16 + r][g];
#pragma unroll
    for (int mi = 0; mi < 2; mi++)
#pragma unroll
      for (int ni = 0; ni < 4; ni++)
        acc[mi][ni] = __builtin_amdgcn_mfma_f32_16x16x32_bf16(av[mi], bv[ni], acc[mi][ni], 0, 0, 0);
  }
  // C/D layout (m89-verified): col = lane&15, row = (lane>>4)*4 + reg
  int rq = (lane >> 4) * 4;
#pragma unroll
  for (int mi = 0; mi < 2; mi++) {
#pragma unroll
    for (int ni = 0; ni < 4; ni++) {
      int col = n0 + wc * 64 + ni * 16 + r;
#pragma unroll
      for (int q = 0; q < 4; q++) {
        int row = row0 + wr * 32 + mi * 16 + rq + q;
        float v = acc[mi][ni][q];
        if constexpr (MODE == 0) {
          v += bias[e * ND + col];
          v = 0.5f * v * (1.f + erff(v * 0.70710678118654752440f));   // exact gelu
          outb[(size_t)row * ND + col] = f2b(v);
        } else {
          outf[(size_t)row * ND + col] = v;
        }
      }
    }
  }
}

// ---------------- combine: out[n] = g0*(y[r0]+b2[e0]) + g1*(y[r1]+b2[e1]) ----------------
__global__ void combine_k(const float* __restrict__ y, const float* __restrict__ b2,
                          const int* __restrict__ token_rows, const int* __restrict__ tok_e,
                          const float* __restrict__ tok_g, float* __restrict__ out) {
  int gid = blockIdx.x * 256 + threadIdx.x;   // NTOK*D_/4 = 524288 total
  int n = gid >> 7;
  int c = (gid & 127) << 2;
  int r0 = token_rows[2 * n], r1 = token_rows[2 * n + 1];
  int e0 = tok_e[2 * n], e1 = tok_e[2 * n + 1];
  float g0 = tok_g[2 * n], g1 = tok_g[2 * n + 1];
  float4 y0 = *(const float4*)&y[(size_t)r0 * D_ + c];
  float4 y1 = *(const float4*)&y[(size_t)r1 * D_ + c];
  float4 c0 = *(const float4*)&b2[e0 * D_ + c];
  float4 c1 = *(const float4*)&b2[e1 * D_ + c];
  float4 o;
  o.x = g0 * (y0.x + c0.x) + g1 * (y1.x + c1.x);
  o.y = g0 * (y0.y + c0.y) + g1 * (y1.y + c1.y);
  o.z = g0 * (y0.z + c0.z) + g1 * (y1.z + c1.z);
  o.w = g0 * (y0.w + c0.w) + g1 * (y1.w + c1.w);
  *(float4*)&out[(size_t)n * D_ + c] = o;
}

extern "C" void kernel_launch(void* const* d_in, const int* in_sizes, int n_in,
                              void* d_out, int out_size, void* d_ws, size_t ws_size,
                              hipStream_t stream) {
  const float* x     = (const float*)d_in[0];
  const float* dt    = (const float*)d_in[1];
  const float* dd    = (const float*)d_in[2];
  const float* dr    = (const float*)d_in[3];
  const float* de    = (const float*)d_in[4];
  const float* cemb  = (const float*)d_in[5];
  const float* Wg    = (const float*)d_in[6];
  const float* bg    = (const float*)d_in[7];
  const float* Wn    = (const float*)d_in[8];
  const float* bn    = (const float*)d_in[9];
  const float* W1    = (const float*)d_in[10];
  const float* b1    = (const float*)d_in[11];
  const float* W2    = (const float*)d_in[12];
  const float* b2    = (const float*)d_in[13];
  const float* noise = (const float*)d_in[14];
  const int*   city  = (const int*)d_in[15];

  float* out   = (float*)d_out;
  float* gate1 = out + (size_t)NTOK * D_;

  char* ws = (char*)d_ws;
  unsigned short* w1T = (unsigned short*)(ws + OFF_W1T);   // [E][H][D] bf16
  unsigned short* w2T = (unsigned short*)(ws + OFF_W2T);   // [E][D][H] bf16
  unsigned short* xg  = (unsigned short*)(ws + OFF_XG);    // [ROWS_CAP][D] bf16
  unsigned short* hid = (unsigned short*)(ws + OFF_HID);   // [ROWS_CAP][H] bf16
  float*  yb          = (float*)(ws + OFF_Y);              // [ROWS_CAP][D] f32
  int*    tok_e       = (int*)(ws + OFF_TOKE);
  float*  tok_g       = (float*)(ws + OFF_TOKG);
  int*    token_rows  = (int*)(ws + OFF_TROWS);
  int*    row_token   = (int*)(ws + OFF_RTOK);
  int*    counts      = (int*)(ws + OFF_CNT);
  int*    cursors     = (int*)(ws + OFF_CUR);
  int*    offsets     = (int*)(ws + OFF_OFFS);
  int*    tile_e      = (int*)(ws + OFF_TE);
  int*    tile_r0     = (int*)(ws + OFF_TR);
  float*  logits_all  = (float*)(ws + OFF_HID);            // aliased scratch (pre-gemm1)

  router_k<<<256, 256, 0, stream>>>(x, dt, dd, dr, de, cemb, city, Wg, Wn,
                                    logits_all, row_token, counts);
  route2_k<<<16, 256, 0, stream>>>(logits_all, bg, bn, noise, gate1, tok_e, tok_g, counts);
  setup_k<<<1, 256, 0, stream>>>(counts, offsets, cursors, tile_e, tile_r0);
  scatter_k<<<16, 256, 0, stream>>>(tok_e, cursors, row_token, token_rows);
  gather_k<<<ROWS_CAP, 128, 0, stream>>>(x, row_token, xg);
  wconv_k<<<dim3(64, 16, E_), 256, 0, stream>>>(W1, w1T, 512, 2048);   // W1 [E][512][2048] -> [E][2048][512]
  wconv_k<<<dim3(16, 64, E_), 256, 0, stream>>>(W2, w2T, 2048, 512);   // W2 [E][2048][512] -> [E][512][2048]
  gemm_k<512, 2048, 0><<<dim3(16, TILES_CAP), 256, 0, stream>>>(xg, w1T, b1, hid, nullptr, tile_e, tile_r0);
  gemm_k<2048, 512, 1><<<dim3(4, TILES_CAP), 256, 0, stream>>>(hid, w2T, nullptr, nullptr, yb, tile_e, tile_r0);
  combine_k<<<2048, 256, 0, stream>>>(yb, b2, token_rows, tok_e, tok_g, out);
}

// Round 3
// 203.236 us; speedup vs baseline: 1.3758x; 1.0396x over previous
//
#include <hip/hip_runtime.h>
#include <hip/hip_bf16.h>

// Problem constants
#define B_      4
#define T_      1024
#define NTOK    4096      // B*T
#define D_      512
#define E_      10
#define H_      2048
#define LIN_    928
#define TOPK    2
#define BM      128       // GEMM row tile (per-expert padding granule)
#define ROWS_CAP 9472     // NTOK*TOPK + E_*BM
#define TILES_CAP 80      // >= sum ceil(n_e/BM) <= 64 + 10

typedef __bf16 bf16x8 __attribute__((ext_vector_type(8)));
typedef float  f32x4  __attribute__((ext_vector_type(4)));

// ---- workspace layout (bytes) ----
// y (f32, 19.4MB) aliases w1T (21MB): w1T is dead after gemm1, y written by gemm2.
// logits scratch (328KB) aliases hid: consumed by route2 before gemm1 writes hid.
#define OFF_W1T   0ull
#define SZ_W1T    (10ull*2048*512*2)            // 20,971,520
#define OFF_W2T   (OFF_W1T + SZ_W1T)
#define SZ_W2T    SZ_W1T
#define OFF_XG    (OFF_W2T + SZ_W2T)            // 41,943,040
#define SZ_XG     ((size_t)ROWS_CAP*512*2)      // 9,699,328
#define OFF_HID   (OFF_XG + SZ_XG)              // 51,642,368
#define SZ_HID    ((size_t)ROWS_CAP*2048*2)     // 38,797,312
#define OFF_Y     OFF_W1T                       // alias (19,398,656 <= 20.97MB)
#define OFF_TOKE  (OFF_HID + SZ_HID)            // 90,439,680
#define OFF_TOKG  (OFF_TOKE + 32768)
#define OFF_TROWS (OFF_TOKG + 32768)
#define OFF_RTOK  (OFF_TROWS + 32768)
#define OFF_CNT   (OFF_RTOK + 38912)
#define OFF_CUR   (OFF_CNT + 64)
#define OFF_OFFS  (OFF_CUR + 64)
#define OFF_TE    (OFF_OFFS + 64)
#define OFF_TR    (OFF_TE + 512)
// total ~90.6 MB

static __device__ __forceinline__ unsigned short f2b(float f) {
  // fp32 -> bf16 round-to-nearest-even (finite values)
  unsigned int u = __float_as_uint(f);
  unsigned int r = (u + 0x7fffu + ((u >> 16) & 1u)) >> 16;
  return (unsigned short)r;
}

// async global -> LDS, 16B per lane; lds dest must be wave-uniform base (HW adds lane*16)
static __device__ __forceinline__ void gld16(const void* g, void* l) {
  __builtin_amdgcn_global_load_lds(
      (const __attribute__((address_space(1))) unsigned int*)g,
      (__attribute__((address_space(3))) unsigned int*)l, 16, 0, 0);
}

// ---------------- router main: raw gate/noise sums, fp32 ----------------
// grid 256 x 256thr; each wave computes 4 tokens x 20 outputs. Folds in init.
__global__ __launch_bounds__(256) void router_k(
    const float* __restrict__ x, const float* __restrict__ dt,
    const float* __restrict__ dd, const float* __restrict__ dr,
    const float* __restrict__ de, const float* __restrict__ cemb,
    const int* __restrict__ city,
    const float* __restrict__ Wg, const float* __restrict__ Wn,
    float* __restrict__ logits_all, int* __restrict__ row_token,
    int* __restrict__ counts) {
  int tid = threadIdx.x;
  int gi = blockIdx.x * 256 + tid;
  if (gi < ROWS_CAP) row_token[gi] = -1;
  if (gi < E_) counts[gi] = 0;

  int lane = tid & 63;
  int gw = blockIdx.x * 4 + (tid >> 6);   // global wave 0..1023
  int n0 = gw * 4;                        // 4 tokens per wave
  int b = n0 >> 10;
  int cb = city[b];

  float acc[4][20];
#pragma unroll
  for (int j = 0; j < 4; j++)
#pragma unroll
    for (int o = 0; o < 20; o++) acc[j][o] = 0.f;

  // city segment (cols 512..543), same value for all 4 tokens
  {
    float hce = (lane < 32) ? cemb[cb * 32 + lane] : 0.f;
    int c = 512 + (lane & 31);
#pragma unroll
    for (int o = 0; o < 10; o++) {
      float wg = Wg[o * LIN_ + c];
      float wn = Wn[o * LIN_ + c];
#pragma unroll
      for (int j = 0; j < 4; j++) {
        acc[j][o]      = fmaf(hce, wg, acc[j][o]);
        acc[j][10 + o] = fmaf(hce, wn, acc[j][10 + o]);
      }
    }
  }

#pragma unroll
  for (int s = 0; s < 5; s++) {
    const float* hp; int W, cofs;
    if      (s == 0) { hp = x;  W = 512; cofs = 0;   }
    else if (s == 1) { hp = dt; W = 128; cofs = 544; }
    else if (s == 2) { hp = dd; W = 128; cofs = 672; }
    else if (s == 3) { hp = dr; W = 64;  cofs = 800; }
    else             { hp = de; W = 64;  cofs = 864; }
    for (int base = 0; base < W; base += 64) {
      int c = cofs + base + lane;
      float wv[20];
#pragma unroll
      for (int o = 0; o < 10; o++) {
        wv[o]      = Wg[o * LIN_ + c];
        wv[10 + o] = Wn[o * LIN_ + c];
      }
      float hv[4];
#pragma unroll
      for (int j = 0; j < 4; j++) hv[j] = hp[(size_t)(n0 + j) * W + base + lane];
#pragma unroll
      for (int j = 0; j < 4; j++)
#pragma unroll
        for (int o = 0; o < 20; o++) acc[j][o] = fmaf(hv[j], wv[o], acc[j][o]);
    }
  }

#pragma unroll
  for (int off = 1; off < 64; off <<= 1) {
#pragma unroll
    for (int j = 0; j < 4; j++)
#pragma unroll
      for (int o = 0; o < 20; o++) acc[j][o] += __shfl_xor(acc[j][o], off);
  }

#pragma unroll
  for (int j = 0; j < 4; j++) {
    float v = 0.f;
#pragma unroll
    for (int o = 0; o < 20; o++) if (lane == o) v = acc[j][o];
    if (lane < 20) logits_all[(size_t)(n0 + j) * 20 + lane] = v;
  }
}

// ---------------- router epilogue: softmax/gate1, noisy top-2 ----------------
__global__ void route2_k(const float* __restrict__ logits_all,
                         const float* __restrict__ bg, const float* __restrict__ bn,
                         const float* __restrict__ noise,
                         float* __restrict__ gate1, int* __restrict__ tok_e,
                         float* __restrict__ tok_g, int* __restrict__ counts) {
  int n = blockIdx.x * 256 + threadIdx.x;
  if (n >= NTOK) return;
  const float* p = &logits_all[(size_t)n * 20];
  float logits[E_], noisy[E_], ex[E_];
  float mx = -3.4e38f;
#pragma unroll
  for (int e = 0; e < E_; e++) { logits[e] = p[e] + bg[e]; mx = fmaxf(mx, logits[e]); }
  float s = 0.f;
#pragma unroll
  for (int e = 0; e < E_; e++) { ex[e] = expf(logits[e] - mx); s += ex[e]; }
  float invs = 1.f / s;
#pragma unroll
  for (int e = 0; e < E_; e++) gate1[(size_t)n * E_ + e] = ex[e] * invs;
#pragma unroll
  for (int e = 0; e < E_; e++) {
    float t = p[10 + e] + bn[e];
    float sp = (t > 20.f) ? t : log1pf(expf(t));   // softplus
    noisy[e] = logits[e] + noise[(size_t)n * E_ + e] * sp;
  }
  int i0 = 0; float v0 = noisy[0];
#pragma unroll
  for (int e = 1; e < E_; e++) if (noisy[e] > v0) { v0 = noisy[e]; i0 = e; }
  int i1 = -1; float v1 = -3.4e38f;
#pragma unroll
  for (int e = 0; e < E_; e++) if (e != i0 && noisy[e] > v1) { v1 = noisy[e]; i1 = e; }
  float ee = expf(v1 - v0);
  float g0 = 1.f / (1.f + ee);
  tok_e[2 * n] = i0; tok_e[2 * n + 1] = i1;
  tok_g[2 * n] = g0; tok_g[2 * n + 1] = ee * g0;
  atomicAdd(&counts[i0], 1); atomicAdd(&counts[i1], 1);
}

// ---------------- setup: prefix sum (padded to BM), tile tables ----------------
__global__ void setup_k(const int* __restrict__ counts, int* __restrict__ offsets,
                        int* __restrict__ cursors, int* __restrict__ tile_e,
                        int* __restrict__ tile_r0) {
  __shared__ int cnt[E_], pf[E_ + 1], tb[E_ + 1];
  int tid = threadIdx.x;
  if (tid < E_) cnt[tid] = counts[tid];
  __syncthreads();
  if (tid == 0) {
    int off = 0, tt = 0;
    for (int e = 0; e < E_; e++) {
      pf[e] = off; tb[e] = tt;
      int nt = (cnt[e] + BM - 1) / BM;
      tt += nt; off += nt * BM;
    }
    pf[E_] = off; tb[E_] = tt;
  }
  __syncthreads();
  if (tid < E_) { offsets[tid] = pf[tid]; cursors[tid] = pf[tid]; }
  if (tid == E_) offsets[E_] = pf[E_];
  if (tid < TILES_CAP) {
    int e = -1;
#pragma unroll
    for (int k = 0; k < E_; k++) if (tid >= tb[k] && tid < tb[k + 1]) e = k;
    if (e >= 0) { tile_e[tid] = e; tile_r0[tid] = pf[e] + (tid - tb[e]) * BM; }
    else        { tile_e[tid] = -1; tile_r0[tid] = 0; }
  }
}

// ---------------- scatter: token -> grouped row ----------------
__global__ void scatter_k(const int* __restrict__ tok_e, int* __restrict__ cursors,
                          int* __restrict__ row_token, int* __restrict__ token_rows) {
  int n = blockIdx.x * blockDim.x + threadIdx.x;
  if (n >= NTOK) return;
  for (int k = 0; k < TOPK; k++) {
    int e = tok_e[2 * n + k];
    int pos = atomicAdd(&cursors[e], 1);
    row_token[pos] = n;
    token_rows[2 * n + k] = pos;
  }
}

// ---------------- gather x rows -> bf16 (padding rows -> 0) ----------------
__global__ void gather_k(const float* __restrict__ x, const int* __restrict__ row_token,
                         unsigned short* __restrict__ xg) {
  int r = blockIdx.x;
  int c = threadIdx.x * 4;   // 128 threads
  int t = row_token[r];
  float4 v = make_float4(0.f, 0.f, 0.f, 0.f);
  if (t >= 0) v = *(const float4*)&x[(size_t)t * D_ + c];
  ushort4 o;
  o.x = f2b(v.x); o.y = f2b(v.y); o.z = f2b(v.z); o.w = f2b(v.w);
  *(ushort4*)&xg[(size_t)r * D_ + c] = o;
}

// ---------------- weight convert + transpose: [E][R][C] f32 -> [E][C][R] bf16 ----------------
// 64x64 tiles, float4 reads, ushort4 writes.
__global__ __launch_bounds__(256) void wconv_k(const float* __restrict__ src,
                                               unsigned short* __restrict__ dst,
                                               int R, int C) {
  __shared__ float t[64][65];
  int e = blockIdx.z;
  int c0 = blockIdx.x << 6, r0 = blockIdx.y << 6;
  int tid = threadIdx.x;
  // read: rows tid>>4 (+16p), cols (tid&15)*4 -> 16 lanes x 16B = 256B/row
  int rr = tid >> 4, cc = (tid & 15) << 2;
  const float* s = src + ((size_t)e * R + r0 + rr) * C + c0 + cc;
#pragma unroll
  for (int p = 0; p < 4; p++) {
    float4 v = *(const float4*)(s + (size_t)p * 16 * C);
    t[rr + p * 16][cc + 0] = v.x; t[rr + p * 16][cc + 1] = v.y;
    t[rr + p * 16][cc + 2] = v.z; t[rr + p * 16][cc + 3] = v.w;
  }
  __syncthreads();
  // write: dst row c = tid>>2, r chunks of 4: r = (tid&3)*4 + p*16
  int wc2 = tid >> 2;
  unsigned short* d = dst + ((size_t)e * C + c0 + wc2) * R + r0;
#pragma unroll
  for (int p = 0; p < 4; p++) {
    int rb = ((tid & 3) << 2) + (p << 4);
    ushort4 o;
    o.x = f2b(t[rb + 0][wc2]); o.y = f2b(t[rb + 1][wc2]);
    o.z = f2b(t[rb + 2][wc2]); o.w = f2b(t[rb + 3][wc2]);
    *(ushort4*)&d[rb] = o;
  }
}

// ---------------- grouped GEMM (m97 structure): C[128x128] = A * BT^T ----------------
// 4 waves (2x2), each 64x64 = 4x4 frags of 16x16x32; BK=32; global_load_lds staging.
// MODE 0: out_bf16 = gelu(acc + bias[e][col])   (GEMM1 -> hid)
// MODE 1: out_f32  = acc                        (GEMM2 -> y)
template<int KD, int ND, int MODE>
__global__ __launch_bounds__(256) void gemm_k(
    const unsigned short* __restrict__ A, const unsigned short* __restrict__ BT,
    const float* __restrict__ bias, unsigned short* __restrict__ outb,
    float* __restrict__ outf,
    const int* __restrict__ tile_e, const int* __restrict__ tile_r0) {
  int e = tile_e[blockIdx.y];
  if (e < 0) return;
  int row0 = tile_r0[blockIdx.y];
  int n0 = blockIdx.x * 128;
  int tid = threadIdx.x;
  int lane = tid & 63, wid = tid >> 6;
  int wr = wid >> 1, wc = wid & 1;             // 2x2 waves, each 64x64
  __shared__ __align__(16) unsigned short As[128 * 32];   // linear, [row][32]
  __shared__ __align__(16) unsigned short Bs[128 * 32];
  f32x4 acc[4][4] = {};
  const unsigned short* Ab = A + (size_t)row0 * KD;
  const unsigned short* Bb = BT + ((size_t)e * ND + n0) * KD;
  // staging: wave covers rows [wid*32, wid*32+32) in 2 issues of 16 rows.
  // lane l -> row += l/4, 16B granule l%4.
  int srow = wid * 32 + (lane >> 2);
  int scol = (lane & 3) * 8;                   // shorts
  const unsigned short* ga = Ab + (size_t)srow * KD + scol;
  const unsigned short* gb = Bb + (size_t)srow * KD + scol;
  unsigned short* lA0 = &As[wid * 1024];       // (wid*32 rows)*32
  unsigned short* lA1 = &As[wid * 1024 + 512]; // +16 rows
  unsigned short* lB0 = &Bs[wid * 1024];
  unsigned short* lB1 = &Bs[wid * 1024 + 512];
  int r = lane & 15, g8 = (lane >> 4) * 8;
  for (int k0 = 0; k0 < KD; k0 += 32) {
    if (k0) __syncthreads();
    gld16(ga + k0, lA0);
    gld16(ga + (size_t)16 * KD + k0, lA1);
    gld16(gb + k0, lB0);
    gld16(gb + (size_t)16 * KD + k0, lB1);
    __syncthreads();   // drains vmcnt(0) before barrier
    bf16x8 av[4], bv[4];
#pragma unroll
    for (int mi = 0; mi < 4; mi++) av[mi] = *(const bf16x8*)&As[(wr * 64 + mi * 16 + r) * 32 + g8];
#pragma unroll
    for (int ni = 0; ni < 4; ni++) bv[ni] = *(const bf16x8*)&Bs[(wc * 64 + ni * 16 + r) * 32 + g8];
#pragma unroll
    for (int mi = 0; mi < 4; mi++)
#pragma unroll
      for (int ni = 0; ni < 4; ni++)
        acc[mi][ni] = __builtin_amdgcn_mfma_f32_16x16x32_bf16(av[mi], bv[ni], acc[mi][ni], 0, 0, 0);
  }
  // C/D layout (m89-verified): col = lane&15, row = (lane>>4)*4 + reg
  int rq = (lane >> 4) * 4;
#pragma unroll
  for (int mi = 0; mi < 4; mi++) {
#pragma unroll
    for (int ni = 0; ni < 4; ni++) {
      int col = n0 + wc * 64 + ni * 16 + r;
      float bz = (MODE == 0) ? bias[e * ND + col] : 0.f;
#pragma unroll
      for (int q = 0; q < 4; q++) {
        int row = row0 + wr * 64 + mi * 16 + rq + q;
        float v = acc[mi][ni][q];
        if constexpr (MODE == 0) {
          v += bz;
          v = 0.5f * v * (1.f + erff(v * 0.70710678118654752440f));   // exact gelu
          outb[(size_t)row * ND + col] = f2b(v);
        } else {
          outf[(size_t)row * ND + col] = v;
        }
      }
    }
  }
}

// ---------------- combine: out[n] = g0*(y[r0]+b2[e0]) + g1*(y[r1]+b2[e1]) ----------------
__global__ void combine_k(const float* __restrict__ y, const float* __restrict__ b2,
                          const int* __restrict__ token_rows, const int* __restrict__ tok_e,
                          const float* __restrict__ tok_g, float* __restrict__ out) {
  int gid = blockIdx.x * 256 + threadIdx.x;   // NTOK*D_/4 = 524288 total
  int n = gid >> 7;
  int c = (gid & 127) << 2;
  int r0 = token_rows[2 * n], r1 = token_rows[2 * n + 1];
  int e0 = tok_e[2 * n], e1 = tok_e[2 * n + 1];
  float g0 = tok_g[2 * n], g1 = tok_g[2 * n + 1];
  float4 y0 = *(const float4*)&y[(size_t)r0 * D_ + c];
  float4 y1 = *(const float4*)&y[(size_t)r1 * D_ + c];
  float4 c0 = *(const float4*)&b2[e0 * D_ + c];
  float4 c1 = *(const float4*)&b2[e1 * D_ + c];
  float4 o;
  o.x = g0 * (y0.x + c0.x) + g1 * (y1.x + c1.x);
  o.y = g0 * (y0.y + c0.y) + g1 * (y1.y + c1.y);
  o.z = g0 * (y0.z + c0.z) + g1 * (y1.z + c1.z);
  o.w = g0 * (y0.w + c0.w) + g1 * (y1.w + c1.w);
  *(float4*)&out[(size_t)n * D_ + c] = o;
}

extern "C" void kernel_launch(void* const* d_in, const int* in_sizes, int n_in,
                              void* d_out, int out_size, void* d_ws, size_t ws_size,
                              hipStream_t stream) {
  const float* x     = (const float*)d_in[0];
  const float* dt    = (const float*)d_in[1];
  const float* dd    = (const float*)d_in[2];
  const float* dr    = (const float*)d_in[3];
  const float* de    = (const float*)d_in[4];
  const float* cemb  = (const float*)d_in[5];
  const float* Wg    = (const float*)d_in[6];
  const float* bg    = (const float*)d_in[7];
  const float* Wn    = (const float*)d_in[8];
  const float* bn    = (const float*)d_in[9];
  const float* W1    = (const float*)d_in[10];
  const float* b1    = (const float*)d_in[11];
  const float* W2    = (const float*)d_in[12];
  const float* b2    = (const float*)d_in[13];
  const float* noise = (const float*)d_in[14];
  const int*   city  = (const int*)d_in[15];

  float* out   = (float*)d_out;
  float* gate1 = out + (size_t)NTOK * D_;

  char* ws = (char*)d_ws;
  unsigned short* w1T = (unsigned short*)(ws + OFF_W1T);   // [E][H][D] bf16
  unsigned short* w2T = (unsigned short*)(ws + OFF_W2T);   // [E][D][H] bf16
  unsigned short* xg  = (unsigned short*)(ws + OFF_XG);    // [ROWS_CAP][D] bf16
  unsigned short* hid = (unsigned short*)(ws + OFF_HID);   // [ROWS_CAP][H] bf16
  float*  yb          = (float*)(ws + OFF_Y);              // [ROWS_CAP][D] f32 (alias w1T)
  int*    tok_e       = (int*)(ws + OFF_TOKE);
  float*  tok_g       = (float*)(ws + OFF_TOKG);
  int*    token_rows  = (int*)(ws + OFF_TROWS);
  int*    row_token   = (int*)(ws + OFF_RTOK);
  int*    counts      = (int*)(ws + OFF_CNT);
  int*    cursors     = (int*)(ws + OFF_CUR);
  int*    offsets     = (int*)(ws + OFF_OFFS);
  int*    tile_e      = (int*)(ws + OFF_TE);
  int*    tile_r0     = (int*)(ws + OFF_TR);
  float*  logits_all  = (float*)(ws + OFF_HID);            // aliased scratch (pre-gemm1)

  router_k<<<256, 256, 0, stream>>>(x, dt, dd, dr, de, cemb, city, Wg, Wn,
                                    logits_all, row_token, counts);
  route2_k<<<16, 256, 0, stream>>>(logits_all, bg, bn, noise, gate1, tok_e, tok_g, counts);
  setup_k<<<1, 256, 0, stream>>>(counts, offsets, cursors, tile_e, tile_r0);
  scatter_k<<<16, 256, 0, stream>>>(tok_e, cursors, row_token, token_rows);
  gather_k<<<ROWS_CAP, 128, 0, stream>>>(x, row_token, xg);
  wconv_k<<<dim3(32, 8, E_), 256, 0, stream>>>(W1, w1T, 512, 2048);   // -> [E][2048][512]
  wconv_k<<<dim3(8, 32, E_), 256, 0, stream>>>(W2, w2T, 2048, 512);   // -> [E][512][2048]
  gemm_k<512, 2048, 0><<<dim3(16, TILES_CAP), 256, 0, stream>>>(xg, w1T, b1, hid, nullptr, tile_e, tile_r0);
  gemm_k<2048, 512, 1><<<dim3(4, TILES_CAP), 256, 0, stream>>>(hid, w2T, nullptr, nullptr, yb, tile_e, tile_r0);
  combine_k<<<2048, 256, 0, stream>>>(yb, b2, token_rows, tok_e, tok_g, out);
}